// Round 18
// baseline (55.179 us; speedup 1.0000x reference)
//
#include <hip/hip_runtime.h>
#include <math.h>

// CTransformer on MI355X, round 18: occupancy lever applied to attn_proj —
// 512 thr / 8 waves per 64-pixel block (16 waves/CU), per-wave 32-row W slices
// ([2][32][32] dbuf, counted vmcnt(2)). Grid 256 halves W staging traffic.
//   k_prep     : byte-identical to round 17
//   k_ln_qkv   : byte-identical to round 17 (8-wave, 3-deep ring)
//   k_attn_proj: this round's change

#define NPIX 16384
#define HW   4096
#define CDIM 256

typedef short  bf16x8 __attribute__((ext_vector_type(8)));
typedef float  f32x4  __attribute__((ext_vector_type(4)));
typedef unsigned short u16x8 __attribute__((ext_vector_type(8)));
typedef unsigned short u16x4 __attribute__((ext_vector_type(4)));

__device__ inline float bf2f(unsigned short u) {
    unsigned v = ((unsigned)u) << 16;
    return __builtin_bit_cast(float, v);
}
__device__ inline unsigned short f2bf(float f) {   // round-to-nearest-even
    unsigned u = __builtin_bit_cast(unsigned, f);
    u += 0x7FFFu + ((u >> 16) & 1u);
    return (unsigned short)(u >> 16);
}
__device__ inline void sb0() { __builtin_amdgcn_sched_barrier(0); }

// ---- prep: weight conversions (float4) + pad vectors -----------------------
__global__ __launch_bounds__(256) void k_prep(const float* __restrict__ Wqkv,
                                              const float* __restrict__ Wout,
                                              const float* __restrict__ bqkv,
                                              const float* __restrict__ lnb,
                                              unsigned short* __restrict__ Wqkvbf,
                                              unsigned short* __restrict__ Woutbf,
                                              float* __restrict__ pads) {
    int bid = blockIdx.x, t = threadIdx.x;
    if (bid < 192) {                       // Wqkv: 49152 float4
        int i = bid * 256 + t;
        float4 v = ((const float4*)Wqkv)[i];
        u16x4 o = { f2bf(v.x), f2bf(v.y), f2bf(v.z), f2bf(v.w) };
        *(u16x4*)(Wqkvbf + i * 4) = o;
    } else if (bid < 256) {                // Wout: 16384 float4
        int i = (bid - 192) * 256 + t;
        float4 v = ((const float4*)Wout)[i];
        u16x4 o = { f2bf(v.x), f2bf(v.y), f2bf(v.z), f2bf(v.w) };
        *(u16x4*)(Woutbf + i * 4) = o;
    } else {                               // pads: 512 dots, 16 lanes each
        int tg = (bid - 256) * 256 + t;
        int d = tg >> 4, part = tg & 15;
        int row = 256 + d;                 // k rows 256..511, v rows 512..767
        const float* wr = Wqkv + (size_t)row * CDIM + part * 16;
        float s = 0.f;
        #pragma unroll
        for (int c = 0; c < 16; ++c) s += lnb[part * 16 + c] * wr[c];
        s += __shfl_xor(s, 1);
        s += __shfl_xor(s, 2);
        s += __shfl_xor(s, 4);
        s += __shfl_xor(s, 8);
        if (part == 0) pads[d] = s + bqkv[row];
    }
}

// ---- per-wave stage: 32 rows x 32 k bf16 (2 KB, 2 gload_lds) ---------------
// Linear dest [32][32] u16; source swizzle: slot s of row r holds chunk
// s ^ ((r>>1)&3).
__device__ inline void stage32x32(const unsigned short* __restrict__ g, int grow0,
                                  int koff, unsigned short* dst, int lane) {
    int rin  = lane >> 2;                  // 0..15
    int slot = lane & 3;
    #pragma unroll
    for (int it = 0; it < 2; ++it) {
        int row = it * 16 + rin;           // 0..31
        const unsigned short* src = g + (size_t)(grow0 + row) * 256 + koff
                                      + ((slot ^ ((row >> 1) & 3)) * 8);
        __builtin_amdgcn_global_load_lds(
            (const __attribute__((address_space(1))) void*)src,
            (__attribute__((address_space(3))) void*)(dst + it * 512),
            16, 0, 0);
    }
}

// ---- FUSED LayerNorm + QKV GEMM (byte-identical to round 17) ----------------
__global__ __launch_bounds__(512, 4) void k_ln_qkv(const float* __restrict__ src,
                                                   const float* __restrict__ lnw,
                                                   const float* __restrict__ lnb,
                                                   const unsigned short* __restrict__ Wbf,
                                                   const float* __restrict__ bias,
                                                   unsigned short* __restrict__ qkvbf) {
    __shared__ unsigned short As[32 * 256];    // 16 KB
    __shared__ unsigned short Ws[8 * 3 * 1024];// 48 KB: per-wave 3-deep ring
    __shared__ float redS[16 * 33 * 2 + 64];   // 4.4 KB dedicated LN scratch

    int t = threadIdx.x;
    int bid = blockIdx.x;
    int sb = (bid & 7) * 64 + (bid >> 3);      // 512 = 8 XCDs x 64, bijective
    int n0 = sb * 32;
    int b = n0 >> 12, p0 = n0 & 4095;
    int lane = t & 63, wv = t >> 6;            // 8 waves
    int lr = lane & 15, lg = lane >> 4;
    unsigned short* WsW = Ws + wv * 3072;      // wave-private 6 KB (3 x 2 KB)

    // prologue: prefetch chunks g=0,1 (drained by the LN barriers)
    stage32x32(Wbf, wv * 32, 0, WsW, lane);            // g0 -> buf0
    stage32x32(Wbf, wv * 32, 32, WsW + 1024, lane);    // g1 -> buf1

    // bias preload (keeps vmem out of the K-loop fence windows)
    float bj[3][2];
    #pragma unroll
    for (int p = 0; p < 3; ++p)
        #pragma unroll
        for (int j = 0; j < 2; ++j)
            bj[p][j] = bias[p * 256 + wv * 32 + j * 16 + lr];

    // ---- LN phase: pix = t&31, q = t>>5 handles 16 channels ----------------
    {
        float* red  = redS;                    // [16][33]
        float* red2 = redS + 528;              // [16][33]
        float* muv  = redS + 1056;             // [32]
        float* rsv  = redS + 1088;             // [32]
        int pix = t & 31, q = t >> 5;          // q 0..15
        const float* sp = src + ((size_t)b * CDIM) * HW + p0 + pix;
        float x[16];
        float sum = 0.f, sq = 0.f;
        #pragma unroll
        for (int i = 0; i < 16; ++i) {
            x[i] = sp[(size_t)(q * 16 + i) * HW];
            sum += x[i]; sq += x[i] * x[i];
        }
        red[q * 33 + pix] = sum; red2[q * 33 + pix] = sq;
        __syncthreads();
        if (t < 32) {
            float s = 0.f, s2 = 0.f;
            #pragma unroll
            for (int qq = 0; qq < 16; ++qq) { s += red[qq * 33 + t]; s2 += red2[qq * 33 + t]; }
            float mu = s * (1.f / 256.f);
            float var = fmaxf(s2 * (1.f / 256.f) - mu * mu, 0.f);
            muv[t] = mu; rsv[t] = rsqrtf(var + 1e-5f);
        }
        __syncthreads();
        float mu = muv[pix], rs = rsv[pix];
        #pragma unroll
        for (int c8 = 0; c8 < 2; ++c8) {
            u16x8 o8;
            #pragma unroll
            for (int j = 0; j < 8; ++j) {
                int c = q * 16 + c8 * 8 + j;
                float xn = (x[c8 * 8 + j] - mu) * rs * lnw[c] + lnb[c];
                o8[j] = f2bf(xn);
            }
            int chunk = q * 2 + c8;            // 0..31
            *(u16x8*)((char*)As + (pix * 512 + (((chunk & 7) ^ (pix & 7)) | (chunk & 24)) * 16)) = o8;
        }
    }
    __syncthreads();   // As visible to all waves. LAST block barrier.

    // ---- K-loop: g = pass*8+kc in [0,24); 3-deep ring, counted vmcnt -------
    for (int pass = 0; pass < 3; ++pass) {
        int d0 = pass * 256;
        f32x4 acc[2][2] = {};
        #pragma unroll
        for (int kc = 0; kc < 8; ++kc) {
            int g = pass * 8 + kc;
            sb0();   // pin prior ds_reads of the ring slot being re-staged
            if (g < 22) {
                int ng = g + 2;
                stage32x32(Wbf, (ng >> 3) * 256 + wv * 32, (ng & 7) * 32,
                           WsW + (ng % 3) * 1024, lane);
                asm volatile("s_waitcnt vmcnt(4)" ::: "memory");   // drain stage(g)
            } else if (g == 22) {
                asm volatile("s_waitcnt vmcnt(2)" ::: "memory");
            } else {
                asm volatile("s_waitcnt vmcnt(0)" ::: "memory");
            }
            sb0();   // pin the reads below AFTER the wait
            const unsigned short* B = WsW + (g % 3) * 1024;
            int chA = kc * 4 + lg;             // As k-chunk 0..31
            bf16x8 a[2], bb[2];
            #pragma unroll
            for (int i = 0; i < 2; ++i) {
                int r = i * 16 + lr;
                int sl = ((chA & 7) ^ (r & 7)) | (chA & 24);
                a[i] = *(bf16x8*)((char*)As + (r * 512 + sl * 16));
            }
            #pragma unroll
            for (int j = 0; j < 2; ++j) {
                int rb = j * 16 + lr;          // wave-local W row 0..31
                int sl = lg ^ ((rb >> 1) & 3);
                bb[j] = *(bf16x8*)(B + rb * 32 + sl * 8);
            }
            __builtin_amdgcn_s_setprio(1);
            #pragma unroll
            for (int i = 0; i < 2; ++i)
                #pragma unroll
                for (int j = 0; j < 2; ++j)
                    acc[i][j] = __builtin_amdgcn_mfma_f32_16x16x32_bf16(
                        a[i], bb[j], acc[i][j], 0, 0, 0);
            __builtin_amdgcn_s_setprio(0);
        }
        // ---- epilogue: Ct = just-read ring slot; in-flight slots disjoint --
        sb0();   // pin kc=7 ds_reads before the ds_writes below
        unsigned short* Ct = WsW + ((pass * 8 + 7) % 3) * 1024;
        #pragma unroll
        for (int j = 0; j < 2; ++j) {
            #pragma unroll
            for (int i = 0; i < 2; ++i)
                #pragma unroll
                for (int r2 = 0; r2 < 4; ++r2) {
                    int row = i * 16 + lg * 4 + r2;   // pixel 0..31
                    int col = j * 16 + lr;            // wave-local d 0..31
                    int ch  = col >> 3;
                    int sl  = ch ^ ((row >> 1) & 3);
                    Ct[row * 32 + sl * 8 + (col & 7)] = f2bf(acc[i][j][r2] + bj[pass][j]);
                }
        }
        #pragma unroll
        for (int it2 = 0; it2 < 2; ++it2) {
            int row = it2 * 16 + (lane >> 2);  // 0..31
            int chunk = lane & 3;              // wave's 32 cols = 4 chunks
            int sl = chunk ^ ((row >> 1) & 3);
            bf16x8 v = *(bf16x8*)(Ct + row * 32 + sl * 8);
            *(bf16x8*)(qkvbf + (size_t)(n0 + row) * 768 + d0 + wv * 32 + chunk * 8) = v;
        }
    }
}

// ---- FUSED attention + out-proj (8 waves, 64-pixel blocks) ------------------
// Block = 64 pixels x 256 out channels; 512 threads. Grid 256, XCD-swizzled.
// Wave wv owns ch rows [wv*32, wv*32+32); W in per-wave [2][32][32] dbuf.
__global__ __launch_bounds__(512, 4) void k_attn_proj(const unsigned short* __restrict__ qkvbf,
                                                      const float* __restrict__ pads,
                                                      const unsigned short* __restrict__ Wbf,
                                                      const float* __restrict__ bias,
                                                      const float* __restrict__ src,
                                                      float* __restrict__ out) {
    __shared__ unsigned short Bt[64 * 264];    // attention out [pix][c] (33.8 KB)
    __shared__ unsigned short Ws[8 * 2048];    // 32 KB: per-wave [2][32][32] dbuf
    int t  = threadIdx.x;
    int bid = blockIdx.x;
    int sb  = (bid & 7) * 32 + (bid >> 3);     // 256 = 8 XCDs x 32, bijective
    int n0 = sb * 64;
    int b  = n0 >> 12;
    int p0 = n0 & 4095;
    int lane = t & 63, wv = t >> 6;            // 8 waves
    int lr = lane & 15, lg = lane >> 4;
    unsigned short* WsW = Ws + wv * 2048;      // wave-private 4 KB

    stage32x32(Wbf, wv * 32, 0, WsW, lane);    // buf0; hides under attention

    // bias preload (keeps vmem out of the fence windows)
    float bd[2][4];
    #pragma unroll
    for (int i = 0; i < 2; ++i)
        #pragma unroll
        for (int r2 = 0; r2 < 4; ++r2)
            bd[i][r2] = bias[wv * 32 + i * 16 + lg * 4 + r2];

    // ---- phase 1: attention, thread = (pixel 0..63, head 0..7) ----
    {
        int pix = t >> 3, h = t & 7;
        int n = n0 + pix;
        int p = n & 4095, hh0 = p >> 6, ww0 = p & 63;
        const float scale = 0.1767766952966369f;  // 1/sqrt(32)

        float qv[32];
        const unsigned short* qp = qkvbf + (size_t)n * 768 + h * 32;
        #pragma unroll
        for (int c8 = 0; c8 < 4; ++c8) {
            bf16x8 v = *(const bf16x8*)(qp + c8 * 8);
            #pragma unroll
            for (int j = 0; j < 8; ++j) qv[c8 * 8 + j] = bf2f((unsigned short)v[j]) * scale;
        }
        float sc[9];
        #pragma unroll
        for (int t9 = 0; t9 < 9; ++t9) {
            int dy = t9 / 3 - 1, dx = t9 % 3 - 1;
            int hh = hh0 + dy, ww = ww0 + dx;
            bool ok = ((unsigned)hh < 64u) && ((unsigned)ww < 64u);
            float a = 0.f;
            if (ok) {
                const unsigned short* kp = qkvbf + (size_t)(n + dy * 64 + dx) * 768 + 256 + h * 32;
                #pragma unroll
                for (int c8 = 0; c8 < 4; ++c8) {
                    bf16x8 v = *(const bf16x8*)(kp + c8 * 8);
                    #pragma unroll
                    for (int j = 0; j < 8; ++j) a += qv[c8 * 8 + j] * bf2f((unsigned short)v[j]);
                }
            } else {
                const float* pk = pads + h * 32;
                #pragma unroll
                for (int j = 0; j < 32; ++j) a += qv[j] * pk[j];
            }
            sc[t9] = a;
        }
        float m = sc[0];
        #pragma unroll
        for (int t9 = 1; t9 < 9; ++t9) m = fmaxf(m, sc[t9]);
        float s = 0.f;
        #pragma unroll
        for (int t9 = 0; t9 < 9; ++t9) { sc[t9] = __expf(sc[t9] - m); s += sc[t9]; }
        float inv = 1.0f / s;

        float ov[32];
        #pragma unroll
        for (int j = 0; j < 32; ++j) ov[j] = 0.f;
        #pragma unroll
        for (int t9 = 0; t9 < 9; ++t9) {
            int dy = t9 / 3 - 1, dx = t9 % 3 - 1;
            int hh = hh0 + dy, ww = ww0 + dx;
            bool ok = ((unsigned)hh < 64u) && ((unsigned)ww < 64u);
            float w = sc[t9] * inv;
            if (ok) {
                const unsigned short* vp = qkvbf + (size_t)(n + dy * 64 + dx) * 768 + 512 + h * 32;
                #pragma unroll
                for (int c8 = 0; c8 < 4; ++c8) {
                    bf16x8 v = *(const bf16x8*)(vp + c8 * 8);
                    #pragma unroll
                    for (int j = 0; j < 8; ++j) ov[c8 * 8 + j] += w * bf2f((unsigned short)v[j]);
                }
            } else {
                const float* pv = pads + 256 + h * 32;
                #pragma unroll
                for (int j = 0; j < 32; ++j) ov[j] += w * pv[j];
            }
        }
        #pragma unroll
        for (int c8 = 0; c8 < 4; ++c8) {
            u16x8 o8;
            #pragma unroll
            for (int j = 0; j < 8; ++j) o8[j] = f2bf(ov[c8 * 8 + j]);
            *(u16x8*)(Bt + pix * 264 + h * 32 + c8 * 8) = o8;
        }
    }
    __syncthreads();   // Bt visible — the only block barrier (drains vmcnt too)

    // ---- phase 2: GEMM 256ch x 64pix x 256k; counted-vmcnt(2) pipeline ----
    f32x4 acc[2][4] = {};
    #pragma unroll
    for (int kc = 0; kc < 8; ++kc) {
        sb0();   // pin prior same-buffer ds_reads BEFORE this stage issue
        if (kc < 7) {
            stage32x32(Wbf, wv * 32, (kc + 1) * 32, WsW + ((kc + 1) & 1) * 1024, lane);
            asm volatile("s_waitcnt vmcnt(2)" ::: "memory");   // drain stage(kc)
        } else {
            asm volatile("s_waitcnt vmcnt(0)" ::: "memory");
        }
        sb0();   // pin the reads below AFTER the wait
        const unsigned short* A = WsW + (kc & 1) * 1024;
        bf16x8 a[2], bb[4];
        #pragma unroll
        for (int i = 0; i < 2; ++i) {
            int ri = i * 16 + lr;              // wave-local W row 0..31
            int sl = lg ^ ((ri >> 1) & 3);
            a[i] = *(bf16x8*)(A + ri * 32 + sl * 8);
        }
        #pragma unroll
        for (int j = 0; j < 4; ++j)
            bb[j] = *(bf16x8*)(Bt + (j * 16 + lr) * 264 + kc * 32 + lg * 8);
        __builtin_amdgcn_s_setprio(1);
        #pragma unroll
        for (int i = 0; i < 2; ++i)
            #pragma unroll
            for (int j = 0; j < 4; ++j)
                acc[i][j] = __builtin_amdgcn_mfma_f32_16x16x32_bf16(
                    a[i], bb[j], acc[i][j], 0, 0, 0);
        __builtin_amdgcn_s_setprio(0);
    }
    #pragma unroll
    for (int i = 0; i < 2; ++i) {
        #pragma unroll
        for (int r2 = 0; r2 < 4; ++r2) {
            int dg = wv * 32 + i * 16 + lg * 4 + r2;
            #pragma unroll
            for (int j = 0; j < 4; ++j) {
                int ng = p0 + j * 16 + lr;
                size_t idx = ((size_t)(b * CDIM + dg)) * HW + ng;
                out[idx] = acc[i][j][r2] + bd[i][r2] + src[idx];
            }
        }
    }
}

extern "C" void kernel_launch(void* const* d_in, const int* in_sizes, int n_in,
                              void* d_out, int out_size, void* d_ws, size_t ws_size,
                              hipStream_t stream) {
    const float* src  = (const float*)d_in[0];
    const float* lnw  = (const float*)d_in[1];
    const float* lnb  = (const float*)d_in[2];
    const float* Wqkv = (const float*)d_in[3];
    const float* bqkv = (const float*)d_in[4];
    const float* Wout = (const float*)d_in[5];
    const float* bout = (const float*)d_in[6];
    float* out = (float*)d_out;

    unsigned short* qkvbf  = (unsigned short*)d_ws;               // 16384*768
    unsigned short* Wqkvbf = qkvbf + (size_t)NPIX * 768;          // 768*256
    unsigned short* Woutbf = Wqkvbf + 768 * 256;                  // 256*256
    float* pads = (float*)(Woutbf + 256 * 256);                   // 512 floats

    k_prep<<<288, 256, 0, stream>>>(Wqkv, Wout, bqkv, lnb, Wqkvbf, Woutbf, pads);
    k_ln_qkv<<<512, 512, 0, stream>>>(src, lnw, lnb, Wqkvbf, bqkv, qkvbf);
    k_attn_proj<<<256, 512, 0, stream>>>(qkvbf, pads, Woutbf, bout, src, out);
}

// Round 19
// 49.373 us; speedup vs baseline: 1.1176x; 1.1176x over previous
//
#include <hip/hip_runtime.h>
#include <math.h>

// CTransformer on MI355X, round 19: REVERT to round-17 champion (49.6 us).
//   k_prep     : Wqkv/Wout fp32->bf16 (float4) + pad vectors
//   k_ln_qkv   : fused LN + QKV GEMM, 512 thr / 8 waves / 32-px blocks,
//                per-wave 32-row W slices in 3-deep gload_lds ring (vmcnt(4))
//   k_attn_proj: fused attention + out-proj, 256 thr / 4 waves / 32-px blocks,
//                per-wave 64-row W slices, [2][64][32] dbuf (vmcnt(4))
// r18's coarse-block occupancy change on attn_proj regressed (barrier-join
// width + block granularity beat raw wave count in this latency regime).

#define NPIX 16384
#define HW   4096
#define CDIM 256

typedef short  bf16x8 __attribute__((ext_vector_type(8)));
typedef float  f32x4  __attribute__((ext_vector_type(4)));
typedef unsigned short u16x8 __attribute__((ext_vector_type(8)));
typedef unsigned short u16x4 __attribute__((ext_vector_type(4)));

__device__ inline float bf2f(unsigned short u) {
    unsigned v = ((unsigned)u) << 16;
    return __builtin_bit_cast(float, v);
}
__device__ inline unsigned short f2bf(float f) {   // round-to-nearest-even
    unsigned u = __builtin_bit_cast(unsigned, f);
    u += 0x7FFFu + ((u >> 16) & 1u);
    return (unsigned short)(u >> 16);
}
__device__ inline void sb0() { __builtin_amdgcn_sched_barrier(0); }

// ---- prep: weight conversions (float4) + pad vectors -----------------------
__global__ __launch_bounds__(256) void k_prep(const float* __restrict__ Wqkv,
                                              const float* __restrict__ Wout,
                                              const float* __restrict__ bqkv,
                                              const float* __restrict__ lnb,
                                              unsigned short* __restrict__ Wqkvbf,
                                              unsigned short* __restrict__ Woutbf,
                                              float* __restrict__ pads) {
    int bid = blockIdx.x, t = threadIdx.x;
    if (bid < 192) {                       // Wqkv: 49152 float4
        int i = bid * 256 + t;
        float4 v = ((const float4*)Wqkv)[i];
        u16x4 o = { f2bf(v.x), f2bf(v.y), f2bf(v.z), f2bf(v.w) };
        *(u16x4*)(Wqkvbf + i * 4) = o;
    } else if (bid < 256) {                // Wout: 16384 float4
        int i = (bid - 192) * 256 + t;
        float4 v = ((const float4*)Wout)[i];
        u16x4 o = { f2bf(v.x), f2bf(v.y), f2bf(v.z), f2bf(v.w) };
        *(u16x4*)(Woutbf + i * 4) = o;
    } else {                               // pads: 512 dots, 16 lanes each
        int tg = (bid - 256) * 256 + t;
        int d = tg >> 4, part = tg & 15;
        int row = 256 + d;                 // k rows 256..511, v rows 512..767
        const float* wr = Wqkv + (size_t)row * CDIM + part * 16;
        float s = 0.f;
        #pragma unroll
        for (int c = 0; c < 16; ++c) s += lnb[part * 16 + c] * wr[c];
        s += __shfl_xor(s, 1);
        s += __shfl_xor(s, 2);
        s += __shfl_xor(s, 4);
        s += __shfl_xor(s, 8);
        if (part == 0) pads[d] = s + bqkv[row];
    }
}

// ---- per-wave stage: 32 rows x 32 k bf16 (2 KB, 2 gload_lds) ---------------
// Linear dest [32][32] u16; source swizzle: slot s of row r holds chunk
// s ^ ((r>>1)&3).
__device__ inline void stage32x32(const unsigned short* __restrict__ g, int grow0,
                                  int koff, unsigned short* dst, int lane) {
    int rin  = lane >> 2;                  // 0..15
    int slot = lane & 3;
    #pragma unroll
    for (int it = 0; it < 2; ++it) {
        int row = it * 16 + rin;           // 0..31
        const unsigned short* src = g + (size_t)(grow0 + row) * 256 + koff
                                      + ((slot ^ ((row >> 1) & 3)) * 8);
        __builtin_amdgcn_global_load_lds(
            (const __attribute__((address_space(1))) void*)src,
            (__attribute__((address_space(3))) void*)(dst + it * 512),
            16, 0, 0);
    }
}

// ---- FUSED LayerNorm + QKV GEMM --------------------------------------------
// Block: 32 pixels x 768 d, 512 threads (8 waves). Grid 512, XCD-swizzled.
// Wave wv owns d-rows [wv*32, wv*32+32) of each 256-d pass; W slices staged in
// a per-wave 3-deep ring ([3][32][32] u16). As[32][256] XOR-chunk swizzled.
__global__ __launch_bounds__(512, 4) void k_ln_qkv(const float* __restrict__ src,
                                                   const float* __restrict__ lnw,
                                                   const float* __restrict__ lnb,
                                                   const unsigned short* __restrict__ Wbf,
                                                   const float* __restrict__ bias,
                                                   unsigned short* __restrict__ qkvbf) {
    __shared__ unsigned short As[32 * 256];    // 16 KB
    __shared__ unsigned short Ws[8 * 3 * 1024];// 48 KB: per-wave 3-deep ring
    __shared__ float redS[16 * 33 * 2 + 64];   // 4.4 KB dedicated LN scratch

    int t = threadIdx.x;
    int bid = blockIdx.x;
    int sb = (bid & 7) * 64 + (bid >> 3);      // 512 = 8 XCDs x 64, bijective
    int n0 = sb * 32;
    int b = n0 >> 12, p0 = n0 & 4095;
    int lane = t & 63, wv = t >> 6;            // 8 waves
    int lr = lane & 15, lg = lane >> 4;
    unsigned short* WsW = Ws + wv * 3072;      // wave-private 6 KB (3 x 2 KB)

    // prologue: prefetch chunks g=0,1 (drained by the LN barriers)
    stage32x32(Wbf, wv * 32, 0, WsW, lane);            // g0 -> buf0
    stage32x32(Wbf, wv * 32, 32, WsW + 1024, lane);    // g1 -> buf1

    // bias preload (keeps vmem out of the K-loop fence windows)
    float bj[3][2];
    #pragma unroll
    for (int p = 0; p < 3; ++p)
        #pragma unroll
        for (int j = 0; j < 2; ++j)
            bj[p][j] = bias[p * 256 + wv * 32 + j * 16 + lr];

    // ---- LN phase: pix = t&31, q = t>>5 handles 16 channels ----------------
    {
        float* red  = redS;                    // [16][33]
        float* red2 = redS + 528;              // [16][33]
        float* muv  = redS + 1056;             // [32]
        float* rsv  = redS + 1088;             // [32]
        int pix = t & 31, q = t >> 5;          // q 0..15
        const float* sp = src + ((size_t)b * CDIM) * HW + p0 + pix;
        float x[16];
        float sum = 0.f, sq = 0.f;
        #pragma unroll
        for (int i = 0; i < 16; ++i) {
            x[i] = sp[(size_t)(q * 16 + i) * HW];
            sum += x[i]; sq += x[i] * x[i];
        }
        red[q * 33 + pix] = sum; red2[q * 33 + pix] = sq;
        __syncthreads();
        if (t < 32) {
            float s = 0.f, s2 = 0.f;
            #pragma unroll
            for (int qq = 0; qq < 16; ++qq) { s += red[qq * 33 + t]; s2 += red2[qq * 33 + t]; }
            float mu = s * (1.f / 256.f);
            float var = fmaxf(s2 * (1.f / 256.f) - mu * mu, 0.f);
            muv[t] = mu; rsv[t] = rsqrtf(var + 1e-5f);
        }
        __syncthreads();
        float mu = muv[pix], rs = rsv[pix];
        #pragma unroll
        for (int c8 = 0; c8 < 2; ++c8) {
            u16x8 o8;
            #pragma unroll
            for (int j = 0; j < 8; ++j) {
                int c = q * 16 + c8 * 8 + j;
                float xn = (x[c8 * 8 + j] - mu) * rs * lnw[c] + lnb[c];
                o8[j] = f2bf(xn);
            }
            int chunk = q * 2 + c8;            // 0..31
            *(u16x8*)((char*)As + (pix * 512 + (((chunk & 7) ^ (pix & 7)) | (chunk & 24)) * 16)) = o8;
        }
    }
    __syncthreads();   // As visible to all waves. LAST block barrier.

    // ---- K-loop: g = pass*8+kc in [0,24); 3-deep ring, counted vmcnt -------
    for (int pass = 0; pass < 3; ++pass) {
        int d0 = pass * 256;
        f32x4 acc[2][2] = {};
        #pragma unroll
        for (int kc = 0; kc < 8; ++kc) {
            int g = pass * 8 + kc;
            sb0();   // pin prior ds_reads of the ring slot being re-staged
            if (g < 22) {
                int ng = g + 2;
                stage32x32(Wbf, (ng >> 3) * 256 + wv * 32, (ng & 7) * 32,
                           WsW + (ng % 3) * 1024, lane);
                asm volatile("s_waitcnt vmcnt(4)" ::: "memory");   // drain stage(g)
            } else if (g == 22) {
                asm volatile("s_waitcnt vmcnt(2)" ::: "memory");
            } else {
                asm volatile("s_waitcnt vmcnt(0)" ::: "memory");
            }
            sb0();   // pin the reads below AFTER the wait
            const unsigned short* B = WsW + (g % 3) * 1024;
            int chA = kc * 4 + lg;             // As k-chunk 0..31
            bf16x8 a[2], bb[2];
            #pragma unroll
            for (int i = 0; i < 2; ++i) {
                int r = i * 16 + lr;
                int sl = ((chA & 7) ^ (r & 7)) | (chA & 24);
                a[i] = *(bf16x8*)((char*)As + (r * 512 + sl * 16));
            }
            #pragma unroll
            for (int j = 0; j < 2; ++j) {
                int rb = j * 16 + lr;          // wave-local W row 0..31
                int sl = lg ^ ((rb >> 1) & 3);
                bb[j] = *(bf16x8*)(B + rb * 32 + sl * 8);
            }
            __builtin_amdgcn_s_setprio(1);
            #pragma unroll
            for (int i = 0; i < 2; ++i)
                #pragma unroll
                for (int j = 0; j < 2; ++j)
                    acc[i][j] = __builtin_amdgcn_mfma_f32_16x16x32_bf16(
                        a[i], bb[j], acc[i][j], 0, 0, 0);
            __builtin_amdgcn_s_setprio(0);
        }
        // ---- epilogue: Ct = just-read ring slot ((pass*8+7)%3); in-flight
        // slots are (g+1)%3,(g+2)%3 — disjoint. Ct[32][32] u16, 2 KB.
        sb0();   // pin kc=7 ds_reads before the ds_writes below
        unsigned short* Ct = WsW + ((pass * 8 + 7) % 3) * 1024;
        #pragma unroll
        for (int j = 0; j < 2; ++j) {
            #pragma unroll
            for (int i = 0; i < 2; ++i)
                #pragma unroll
                for (int r2 = 0; r2 < 4; ++r2) {
                    int row = i * 16 + lg * 4 + r2;   // pixel 0..31
                    int col = j * 16 + lr;            // wave-local d 0..31
                    int ch  = col >> 3;
                    int sl  = ch ^ ((row >> 1) & 3);
                    Ct[row * 32 + sl * 8 + (col & 7)] = f2bf(acc[i][j][r2] + bj[pass][j]);
                }
        }
        #pragma unroll
        for (int it2 = 0; it2 < 2; ++it2) {
            int row = it2 * 16 + (lane >> 2);  // 0..31
            int chunk = lane & 3;              // wave's 32 cols = 4 chunks
            int sl = chunk ^ ((row >> 1) & 3);
            bf16x8 v = *(bf16x8*)(Ct + row * 32 + sl * 8);
            *(bf16x8*)(qkvbf + (size_t)(n0 + row) * 768 + d0 + wv * 32 + chunk * 8) = v;
        }
    }
}

// ---- per-wave stage (attn_proj): 64 rows x 32 k bf16 via gload_lds ----------
__device__ inline void stage32(const unsigned short* __restrict__ g, int grow0,
                               int koff, unsigned short* dst, int lane) {
    int r16  = lane >> 2;
    int slot = lane & 3;
    #pragma unroll
    for (int it = 0; it < 4; ++it) {
        int row = it * 16 + r16;           // wave-local 0..63
        const unsigned short* src = g + (size_t)(grow0 + row) * 256 + koff
                                      + ((slot ^ ((row >> 1) & 3)) * 8);
        __builtin_amdgcn_global_load_lds(
            (const __attribute__((address_space(1))) void*)src,
            (__attribute__((address_space(3))) void*)(dst + it * 16 * 32),
            16, 0, 0);
    }
}

__global__ __launch_bounds__(256, 3) void k_attn_proj(const unsigned short* __restrict__ qkvbf,
                                                      const float* __restrict__ pads,
                                                      const unsigned short* __restrict__ Wbf,
                                                      const float* __restrict__ bias,
                                                      const float* __restrict__ src,
                                                      float* __restrict__ out) {
    __shared__ unsigned short Bt[32 * 264];    // attention out [pix][c] (16.9 KB)
    __shared__ unsigned short Ws[4 * 4096];    // 32 KB: per-wave [2][64][32] dbuf
    int t  = threadIdx.x;
    int bid = blockIdx.x;
    int sb  = (bid & 7) * 64 + (bid >> 3);     // 512 = 8 XCDs x 64, bijective
    int n0 = sb * 32;
    int b  = n0 >> 12;
    int p0 = n0 & 4095;
    int lane = t & 63, wv = t >> 6;
    int lr = lane & 15, lg = lane >> 4;
    unsigned short* WsW = Ws + wv * 4096;      // wave-private 8 KB

    stage32(Wbf, wv * 64, 0, WsW, lane);       // buf0; hides under attention

    float bd[4][4];
    #pragma unroll
    for (int i = 0; i < 4; ++i)
        #pragma unroll
        for (int r2 = 0; r2 < 4; ++r2)
            bd[i][r2] = bias[wv * 64 + i * 16 + lg * 4 + r2];

    // ---- phase 1: attention, thread = (pixel, head) ----
    {
        int pix = t >> 3, h = t & 7;
        int n = n0 + pix;
        int p = n & 4095, hh0 = p >> 6, ww0 = p & 63;
        const float scale = 0.1767766952966369f;  // 1/sqrt(32)

        float qv[32];
        const unsigned short* qp = qkvbf + (size_t)n * 768 + h * 32;
        #pragma unroll
        for (int c8 = 0; c8 < 4; ++c8) {
            bf16x8 v = *(const bf16x8*)(qp + c8 * 8);
            #pragma unroll
            for (int j = 0; j < 8; ++j) qv[c8 * 8 + j] = bf2f((unsigned short)v[j]) * scale;
        }
        float sc[9];
        #pragma unroll
        for (int t9 = 0; t9 < 9; ++t9) {
            int dy = t9 / 3 - 1, dx = t9 % 3 - 1;
            int hh = hh0 + dy, ww = ww0 + dx;
            bool ok = ((unsigned)hh < 64u) && ((unsigned)ww < 64u);
            float a = 0.f;
            if (ok) {
                const unsigned short* kp = qkvbf + (size_t)(n + dy * 64 + dx) * 768 + 256 + h * 32;
                #pragma unroll
                for (int c8 = 0; c8 < 4; ++c8) {
                    bf16x8 v = *(const bf16x8*)(kp + c8 * 8);
                    #pragma unroll
                    for (int j = 0; j < 8; ++j) a += qv[c8 * 8 + j] * bf2f((unsigned short)v[j]);
                }
            } else {
                const float* pk = pads + h * 32;
                #pragma unroll
                for (int j = 0; j < 32; ++j) a += qv[j] * pk[j];
            }
            sc[t9] = a;
        }
        float m = sc[0];
        #pragma unroll
        for (int t9 = 1; t9 < 9; ++t9) m = fmaxf(m, sc[t9]);
        float s = 0.f;
        #pragma unroll
        for (int t9 = 0; t9 < 9; ++t9) { sc[t9] = __expf(sc[t9] - m); s += sc[t9]; }
        float inv = 1.0f / s;

        float ov[32];
        #pragma unroll
        for (int j = 0; j < 32; ++j) ov[j] = 0.f;
        #pragma unroll
        for (int t9 = 0; t9 < 9; ++t9) {
            int dy = t9 / 3 - 1, dx = t9 % 3 - 1;
            int hh = hh0 + dy, ww = ww0 + dx;
            bool ok = ((unsigned)hh < 64u) && ((unsigned)ww < 64u);
            float w = sc[t9] * inv;
            if (ok) {
                const unsigned short* vp = qkvbf + (size_t)(n + dy * 64 + dx) * 768 + 512 + h * 32;
                #pragma unroll
                for (int c8 = 0; c8 < 4; ++c8) {
                    bf16x8 v = *(const bf16x8*)(vp + c8 * 8);
                    #pragma unroll
                    for (int j = 0; j < 8; ++j) ov[c8 * 8 + j] += w * bf2f((unsigned short)v[j]);
                }
            } else {
                const float* pv = pads + 256 + h * 32;
                #pragma unroll
                for (int j = 0; j < 32; ++j) ov[j] += w * pv[j];
            }
        }
        #pragma unroll
        for (int c8 = 0; c8 < 4; ++c8) {
            u16x8 o8;
            #pragma unroll
            for (int j = 0; j < 8; ++j) o8[j] = f2bf(ov[c8 * 8 + j]);
            *(u16x8*)(Bt + pix * 264 + h * 32 + c8 * 8) = o8;
        }
    }
    __syncthreads();   // Bt visible — the only block barrier (drains vmcnt too)

    // ---- phase 2: GEMM 256ch x 32pix x 256k; counted-vmcnt pipeline ----
    f32x4 acc[4][2] = {};
    #pragma unroll
    for (int kc = 0; kc < 8; ++kc) {
        sb0();   // pin prior same-buffer ds_reads BEFORE this stage issue
        if (kc < 7) {
            stage32(Wbf, wv * 64, (kc + 1) * 32, WsW + ((kc + 1) & 1) * 2048, lane);
            asm volatile("s_waitcnt vmcnt(4)" ::: "memory");
        } else {
            asm volatile("s_waitcnt vmcnt(0)" ::: "memory");
        }
        sb0();   // pin the reads below AFTER the wait
        const unsigned short* A = WsW + (kc & 1) * 2048;
        bf16x8 a[4], bb[2];
        #pragma unroll
        for (int i = 0; i < 4; ++i) {
            int ri = i * 16 + lr;              // wave-local W row 0..63
            int sl = lg ^ ((ri >> 1) & 3);
            a[i] = *(bf16x8*)(A + ri * 32 + sl * 8);
        }
        #pragma unroll
        for (int j = 0; j < 2; ++j)
            bb[j] = *(bf16x8*)(Bt + (j * 16 + lr) * 264 + kc * 32 + lg * 8);
        __builtin_amdgcn_s_setprio(1);
        #pragma unroll
        for (int i = 0; i < 4; ++i)
            #pragma unroll
            for (int j = 0; j < 2; ++j)
                acc[i][j] = __builtin_amdgcn_mfma_f32_16x16x32_bf16(
                    a[i], bb[j], acc[i][j], 0, 0, 0);
        __builtin_amdgcn_s_setprio(0);
    }
    #pragma unroll
    for (int i = 0; i < 4; ++i) {
        #pragma unroll
        for (int r2 = 0; r2 < 4; ++r2) {
            int dg = wv * 64 + i * 16 + lg * 4 + r2;
            #pragma unroll
            for (int j = 0; j < 2; ++j) {
                int ng = p0 + j * 16 + lr;
                size_t idx = ((size_t)(b * CDIM + dg)) * HW + ng;
                out[idx] = acc[i][j][r2] + bd[i][r2] + src[idx];
            }
        }
    }
}

extern "C" void kernel_launch(void* const* d_in, const int* in_sizes, int n_in,
                              void* d_out, int out_size, void* d_ws, size_t ws_size,
                              hipStream_t stream) {
    const float* src  = (const float*)d_in[0];
    const float* lnw  = (const float*)d_in[1];
    const float* lnb  = (const float*)d_in[2];
    const float* Wqkv = (const float*)d_in[3];
    const float* bqkv = (const float*)d_in[4];
    const float* Wout = (const float*)d_in[5];
    const float* bout = (const float*)d_in[6];
    float* out = (float*)d_out;

    unsigned short* qkvbf  = (unsigned short*)d_ws;               // 16384*768
    unsigned short* Wqkvbf = qkvbf + (size_t)NPIX * 768;          // 768*256
    unsigned short* Woutbf = Wqkvbf + 768 * 256;                  // 256*256
    float* pads = (float*)(Woutbf + 256 * 256);                   // 512 floats

    k_prep<<<288, 256, 0, stream>>>(Wqkv, Wout, bqkv, lnb, Wqkvbf, Woutbf, pads);
    k_ln_qkv<<<512, 512, 0, stream>>>(src, lnw, lnb, Wqkvbf, bqkv, qkvbf);
    k_attn_proj<<<512, 256, 0, stream>>>(qkvbf, pads, Woutbf, bout, src, out);
}